// Round 2
// baseline (713.395 us; speedup 1.0000x reference)
//
#include <hip/hip_runtime.h>
#include <hip/hip_bf16.h>
#include <math.h>

// Problem constants (MambaAgent reference)
#define B_   16
#define L_   1024
#define DM   512          // D_MODEL
#define DI   1024         // D_INNER
#define NST  16           // D_STATE
#define DTR  32           // DT_RANK
#define ML   (B_*L_)      // 16384 rows

typedef __hip_bfloat16 bf16;

__device__ __forceinline__ float bf2f(unsigned short u) {
  union { unsigned int i; float f; } v; v.i = ((unsigned int)u) << 16; return v.f;
}
__device__ __forceinline__ float sigmoidf_(float v) { return 1.f/(1.f+__expf(-v)); }

// ---- dtype-polymorphic loads: T = storage type of INPUT tensors ----
template<typename T> struct WT;
template<> struct WT<bf16> {
  static __device__ __forceinline__ float ld(const void* p, size_t i) {
    return bf2f(((const unsigned short*)p)[i]);
  }
  static __device__ __forceinline__ void ld4(const void* p, size_t i, float* d) {
    const ushort4 v = *(const ushort4*)((const unsigned short*)p + i);
    d[0]=bf2f(v.x); d[1]=bf2f(v.y); d[2]=bf2f(v.z); d[3]=bf2f(v.w);
  }
};
template<> struct WT<float> {
  static __device__ __forceinline__ float ld(const void* p, size_t i) {
    return ((const float*)p)[i];
  }
  static __device__ __forceinline__ void ld4(const void* p, size_t i, float* d) {
    const float4 v = *(const float4*)((const float*)p + i);
    d[0]=v.x; d[1]=v.y; d[2]=v.z; d[3]=v.w;
  }
};

// ---- dtype detect: low u16 of each u32 word of x. bf16 buffer -> bf16 N(0,1)
// samples (sane magnitude, ~100%); fp32 buffer -> mantissa bits (sane ~4%). ----
__global__ void detect_k(const unsigned int* __restrict__ x, int* __restrict__ flag) {
  int tid = threadIdx.x;
  int cnt = 0;
  for (int i = tid; i < 256; i += 64) {
    float a = fabsf(bf2f((unsigned short)(x[i] & 0xffffu)));
    if (a > 1e-3f && a < 10.f) cnt++;
  }
  for (int off = 32; off >= 1; off >>= 1) cnt += __shfl_xor(cnt, off);
  if (tid == 0) *flag = (cnt >= 128) ? 1 : 0;
}

// ---- generic C[m,n] = epi( sum_k A[m*lda+k]*W[n*ldb+k] + bias[n] ) ----
// mode 0: plain, 1: +bias,silu, 2: +bias,softplus.  M%64==0, N%64==0, K%16==0.
template<typename TA, typename TWt>
__device__ __forceinline__ void gemm_body(
    const void* __restrict__ A, const void* __restrict__ W,
    const void* __restrict__ bias, float* __restrict__ C,
    int K, int lda, int ldb, int ldc, int mode)
{
  __shared__ float As[16][68];
  __shared__ float Bs[16][68];
  const int tid = threadIdx.x;
  const int m0 = blockIdx.x * 64;
  const int n0 = blockIdx.y * 64;
  const int tx = tid & 15, ty = tid >> 4;
  const int lrow = tid >> 2;        // 0..63
  const int lk4  = (tid & 3) * 4;   // 0,4,8,12
  float acc[4][4] = {};
  for (int k0 = 0; k0 < K; k0 += 16) {
    float av[4], bv[4];
    WT<TA >::ld4(A, (size_t)(m0 + lrow) * lda + k0 + lk4, av);
    WT<TWt>::ld4(W, (size_t)(n0 + lrow) * ldb + k0 + lk4, bv);
    __syncthreads();
    #pragma unroll
    for (int q = 0; q < 4; ++q) { As[lk4+q][lrow] = av[q]; Bs[lk4+q][lrow] = bv[q]; }
    __syncthreads();
    #pragma unroll
    for (int k = 0; k < 16; ++k) {
      float4 a4 = *(const float4*)&As[k][ty*4];
      float4 b4 = *(const float4*)&Bs[k][tx*4];
      float aa[4] = {a4.x, a4.y, a4.z, a4.w};
      float bb[4] = {b4.x, b4.y, b4.z, b4.w};
      #pragma unroll
      for (int i = 0; i < 4; ++i)
        #pragma unroll
        for (int j = 0; j < 4; ++j)
          acc[i][j] += aa[i] * bb[j];
    }
  }
  #pragma unroll
  for (int i = 0; i < 4; ++i) {
    int m = m0 + ty*4 + i;
    int n = n0 + tx*4;
    float o[4];
    #pragma unroll
    for (int j = 0; j < 4; ++j) {
      float v = acc[i][j];
      if (mode >= 1) v += WT<TWt>::ld(bias, n + j);
      if (mode == 1) v = v * sigmoidf_(v);
      else if (mode == 2) v = (v > 20.f) ? v : log1pf(__expf(v));
      o[j] = v;
    }
    *(float4*)&C[(size_t)m * ldc + n] = make_float4(o[0], o[1], o[2], o[3]);
  }
}

// A is a raw INPUT tensor (dtype = flag)
__global__ __launch_bounds__(256) void gemm_in_k(const void* A, const void* W,
    const void* bias, float* C, int K, int lda, int ldb, int ldc, int mode,
    const int* __restrict__ flag)
{
  if (*flag) gemm_body<bf16, bf16>(A, W, bias, C, K, lda, ldb, ldc, mode);
  else       gemm_body<float, float>(A, W, bias, C, K, lda, ldb, ldc, mode);
}
// A is an fp32 workspace tensor
__global__ __launch_bounds__(256) void gemm_ws_k(const void* A, const void* W,
    const void* bias, float* C, int K, int lda, int ldb, int ldc, int mode,
    const int* __restrict__ flag)
{
  if (*flag) gemm_body<float, bf16>(A, W, bias, C, K, lda, ldb, ldc, mode);
  else       gemm_body<float, float>(A, W, bias, C, K, lda, ldb, ldc, mode);
}

// ---- z (gate) only needed at last token ----
template<typename TWt>
__device__ __forceinline__ void zlast_body(const float* __restrict__ embed,
    const void* __restrict__ W_in, float* __restrict__ z_last)
{
  int b = blockIdx.x;
  __shared__ float e[DM];
  for (int i = threadIdx.x; i < DM; i += 256) e[i] = embed[(size_t)(b*L_ + L_-1)*DM + i];
  __syncthreads();
  for (int j = threadIdx.x; j < DI; j += 256) {
    size_t roff = (size_t)(DI + j)*DM;
    float acc = 0.f;
    for (int k = 0; k < DM; ++k) acc += e[k]*WT<TWt>::ld(W_in, roff + k);
    z_last[b*DI + j] = acc;
  }
}
__global__ __launch_bounds__(256) void zlast_k(const float* embed, const void* W_in,
    float* z_last, const int* __restrict__ flag)
{
  if (*flag) zlast_body<bf16>(embed, W_in, z_last);
  else       zlast_body<float>(embed, W_in, z_last);
}

// ---- causal depthwise conv + silu ----
template<typename TWt>
__device__ __forceinline__ void conv_body(const float* __restrict__ xu,
    const void* __restrict__ conv_w, const void* __restrict__ conv_b,
    float* __restrict__ u)
{
  int bi = blockIdx.x;                    // 1024 blocks = b(16) x tc(16) x dchunk(4)
  int d  = (bi & 3)*256 + threadIdx.x;
  int tc = (bi >> 2) & 15;
  int b  = bi >> 6;
  float w[4];
  WT<TWt>::ld4(conv_w, (size_t)d*4, w);
  float bias = WT<TWt>::ld(conv_b, d);
  int t0 = tc*64;
  const float* base = xu + (size_t)b*L_*DI + d;
  float* ubase = u + (size_t)b*L_*DI + d;
  float xm3 = (t0-3 >= 0) ? base[(size_t)(t0-3)*DI] : 0.f;
  float xm2 = (t0-2 >= 0) ? base[(size_t)(t0-2)*DI] : 0.f;
  float xm1 = (t0-1 >= 0) ? base[(size_t)(t0-1)*DI] : 0.f;
  for (int t = t0; t < t0+64; ++t) {
    float cur = base[(size_t)t*DI];
    float v = w[0]*xm3 + w[1]*xm2 + w[2]*xm1 + w[3]*cur + bias;
    ubase[(size_t)t*DI] = v * sigmoidf_(v);
    xm3 = xm2; xm2 = xm1; xm1 = cur;
  }
}
__global__ __launch_bounds__(256) void conv_k(const float* xu, const void* conv_w,
    const void* conv_b, float* u, const int* __restrict__ flag)
{
  if (*flag) conv_body<bf16>(xu, conv_w, conv_b, u);
  else       conv_body<float>(xu, conv_w, conv_b, u);
}

// ---- selective scan: thread = (dl 0..15, n 0..15); only last-token y needed ----
template<typename TWt>
__device__ __forceinline__ void scan_body(const float* __restrict__ delta,
    const float* __restrict__ u, const float* __restrict__ xdbl,
    const void* __restrict__ A_log, float* __restrict__ y_scan)
{
  int b = blockIdx.x;
  int d0 = blockIdx.y * 16;
  int tid = threadIdx.x;
  int n = tid & 15, dl = tid >> 4;
  int d = d0 + dl;
  float a = -__expf(WT<TWt>::ld(A_log, (size_t)d*NST + n));
  __shared__ float sD[128*16], sU[128*16], sB[128*16];
  float h = 0.f;
  for (int t0 = 0; t0 < L_; t0 += 128) {
    __syncthreads();
    for (int i = tid; i < 128*16; i += 256) {
      int tt = i >> 4, q = i & 15;
      size_t row = (size_t)(b*L_ + t0 + tt);
      sD[i] = delta[row*DI + d0 + q];
      sU[i] = u[row*DI + d0 + q];
      sB[i] = xdbl[row*64 + DTR + q];
    }
    __syncthreads();
    #pragma unroll 8
    for (int t = 0; t < 128; ++t) {
      float dt = sD[t*16 + dl];
      float ut = sU[t*16 + dl];
      float bn = sB[t*16 + n];
      h = __expf(dt * a) * h + dt * ut * bn;
    }
  }
  float c = xdbl[(size_t)(b*L_ + L_-1)*64 + DTR + NST + n];
  float p = h * c;
  p += __shfl_xor(p, 1);
  p += __shfl_xor(p, 2);
  p += __shfl_xor(p, 4);
  p += __shfl_xor(p, 8);
  if (n == 0) y_scan[b*DI + d] = p;
}
__global__ __launch_bounds__(256) void scan_k(const float* delta, const float* u,
    const float* xdbl, const void* A_log, float* y_scan, const int* __restrict__ flag)
{
  if (*flag) scan_body<bf16>(delta, u, xdbl, A_log, y_scan);
  else       scan_body<float>(delta, u, xdbl, A_log, y_scan);
}

// ---- last-token epilogue: y*silu(z) -> W_out -> layernorm -> silu -> 17 heads ----
template<typename TWt>
__device__ __forceinline__ void head_body(const float* __restrict__ y_scan,
    const float* __restrict__ u, const float* __restrict__ z_last,
    const void* __restrict__ Dskip, const void* __restrict__ W_out,
    const void* __restrict__ W_critic, const void* __restrict__ b_critic,
    const void* __restrict__ W_amean, const void* __restrict__ b_amean,
    const void* __restrict__ W_astd, const void* __restrict__ b_astd,
    void* __restrict__ out)
{
  int b = blockIdx.x;
  int tid = threadIdx.x;
  __shared__ float yz[DI];
  __shared__ float nb[DM];
  __shared__ float w1[8], w2[8];
  for (int i = tid; i < DI; i += 512) {
    float ys = y_scan[b*DI + i] + u[(size_t)(b*L_ + L_-1)*DI + i] * WT<TWt>::ld(Dskip, i);
    float z = z_last[b*DI + i];
    yz[i] = ys * (z * sigmoidf_(z));
  }
  __syncthreads();
  float m = 0.f;
  {
    size_t roff = (size_t)tid * DI;
    for (int k = 0; k < DI; ++k) m += yz[k] * WT<TWt>::ld(W_out, roff + k);
  }
  float s1 = m, s2 = m*m;
  for (int off = 32; off >= 1; off >>= 1) { s1 += __shfl_xor(s1, off); s2 += __shfl_xor(s2, off); }
  int wid = tid >> 6, lane = tid & 63;
  if (lane == 0) { w1[wid] = s1; w2[wid] = s2; }
  __syncthreads();
  float t1 = 0.f, t2 = 0.f;
  for (int i = 0; i < 8; ++i) { t1 += w1[i]; t2 += w2[i]; }
  float mu  = t1 * (1.f/DM);
  float var = t2 * (1.f/DM) - mu*mu;
  float v = (m - mu) * rsqrtf(var + 1e-5f);
  nb[tid] = v * sigmoidf_(v);
  __syncthreads();
  for (int o = wid; o < 17; o += 8) {
    const void* w; size_t woff; float bias;
    if (o < 8)       { w = W_amean; woff = (size_t)o*DM;     bias = WT<TWt>::ld(b_amean, o); }
    else if (o < 16) { w = W_astd;  woff = (size_t)(o-8)*DM; bias = WT<TWt>::ld(b_astd, o-8); }
    else             { w = W_critic; woff = 0;               bias = WT<TWt>::ld(b_critic, 0); }
    float p = 0.f;
    for (int j = lane; j < DM; j += 64) p += nb[j] * WT<TWt>::ld(w, woff + j);
    for (int off = 32; off >= 1; off >>= 1) p += __shfl_xor(p, off);
    if (lane == 0) {
      float r = p + bias;
      int idx; float val;
      if (o < 8)       { idx = b*8 + o;           val = r; }
      else if (o < 16) { float ls = fminf(1.f, fmaxf(-1.f, r));
                         idx = 128 + b*8 + (o-8); val = expf(ls); }
      else             { idx = 256 + b;           val = r; }
      if (sizeof(TWt) == 2) ((bf16*)out)[idx] = __float2bfloat16(val);
      else                  ((float*)out)[idx] = val;
    }
  }
}
__global__ __launch_bounds__(512) void head_k(const float* y_scan, const float* u,
    const float* z_last, const void* Dskip, const void* W_out,
    const void* W_critic, const void* b_critic, const void* W_amean,
    const void* b_amean, const void* W_astd, const void* b_astd,
    void* out, const int* __restrict__ flag)
{
  if (*flag) head_body<bf16>(y_scan, u, z_last, Dskip, W_out, W_critic, b_critic,
                             W_amean, b_amean, W_astd, b_astd, out);
  else       head_body<float>(y_scan, u, z_last, Dskip, W_out, W_critic, b_critic,
                              W_amean, b_amean, W_astd, b_astd, out);
}

extern "C" void kernel_launch(void* const* d_in, const int* in_sizes, int n_in,
                              void* d_out, int out_size, void* d_ws, size_t ws_size,
                              hipStream_t stream)
{
  const void* x        = d_in[0];
  const void* W_emb    = d_in[1];
  const void* b_emb    = d_in[2];
  const void* W_in     = d_in[3];
  const void* conv_w   = d_in[4];
  const void* conv_b   = d_in[5];
  const void* W_xproj  = d_in[6];
  const void* W_dt     = d_in[7];
  const void* b_dt     = d_in[8];
  const void* A_log    = d_in[9];
  const void* Dskip    = d_in[10];
  const void* W_out    = d_in[11];
  const void* W_critic = d_in[12];
  const void* b_critic = d_in[13];
  const void* W_amean  = d_in[14];
  const void* b_amean  = d_in[15];
  const void* W_astd   = d_in[16];
  const void* b_astd   = d_in[17];

  // workspace layout (fp32 intermediates): 32+64+64+4 MB + small = ~164.2 MB
  char* ws = (char*)d_ws;
  float* embed = (float*)ws; ws += (size_t)ML*DM*sizeof(float);
  float* xu    = (float*)ws; ws += (size_t)ML*DI*sizeof(float);
  float* uu    = (float*)ws; ws += (size_t)ML*DI*sizeof(float);
  float* xdbl  = (float*)ws; ws += (size_t)ML*64*sizeof(float);
  float* zlast = (float*)ws; ws += (size_t)B_*DI*sizeof(float);
  float* yscan = (float*)ws; ws += (size_t)B_*DI*sizeof(float);
  int*   flag  = (int*)ws;   ws += 64;
  float* delta = xu;  // xu is dead after conv; reuse for delta

  // 0. detect input dtype (bf16 vs fp32) from x's bit patterns
  detect_k<<<1, 64, 0, stream>>>((const unsigned int*)x, flag);
  // 1. embed = silu(x @ W_emb^T + b_emb)
  gemm_in_k<<<dim3(ML/64, DM/64), 256, 0, stream>>>(x, W_emb, b_emb, embed, 32, 32, 32, DM, 1, flag);
  // 2. xu = embed @ W_in[:DI]^T   (the 17 GF hot GEMM)
  gemm_ws_k<<<dim3(ML/64, DI/64), 256, 0, stream>>>(embed, W_in, nullptr, xu, DM, DM, DM, DI, 0, flag);
  // 2b. z at last token only
  zlast_k<<<16, 256, 0, stream>>>(embed, W_in, zlast, flag);
  // 3. u = silu(causal depthwise conv(xu))
  conv_k<<<1024, 256, 0, stream>>>(xu, conv_w, conv_b, uu, flag);
  // 4. x_dbl = u @ W_xproj^T  (dt | B | C)
  gemm_ws_k<<<dim3(ML/64, 1), 256, 0, stream>>>(uu, W_xproj, nullptr, xdbl, DI, DI, DI, 64, 0, flag);
  // 5. delta = softplus(dt @ W_dt^T + b_dt)  (overwrites xu)
  gemm_ws_k<<<dim3(ML/64, DI/64), 256, 0, stream>>>(xdbl, W_dt, b_dt, delta, 32, 64, 32, DI, 2, flag);
  // 6. selective scan -> y at last token
  scan_k<<<dim3(B_, DI/16), 256, 0, stream>>>(delta, uu, xdbl, A_log, yscan, flag);
  // 7. gate, out-proj, layernorm, silu, heads
  head_k<<<16, 512, 0, stream>>>(yscan, uu, zlast, Dskip, W_out, W_critic, b_critic,
                                 W_amean, b_amean, W_astd, b_astd, (void*)d_out, flag);
}

// Round 4
// 509.405 us; speedup vs baseline: 1.4004x; 1.4004x over previous
//
#include <hip/hip_runtime.h>
#include <hip/hip_bf16.h>
#include <math.h>

// Problem constants (MambaAgent reference)
#define B_   16
#define L_   1024
#define DM   512          // D_MODEL
#define DI   1024         // D_INNER
#define NST  16           // D_STATE
#define DTR  32           // DT_RANK
#define ML   (B_*L_)      // 16384 rows

typedef __hip_bfloat16 bf16;
typedef __attribute__((ext_vector_type(8))) short short8;
typedef __attribute__((ext_vector_type(4))) float f32x4;

__device__ __forceinline__ float bf2f(unsigned short u) {
  union { unsigned int i; float f; } v; v.i = ((unsigned int)u) << 16; return v.f;
}
__device__ __forceinline__ unsigned short f2bfbits(float f) {
  bf16 h = __float2bfloat16(f);
  return *(unsigned short*)&h;
}
__device__ __forceinline__ float sigmoidf_(float v) { return 1.f/(1.f+__expf(-v)); }

// ---- dtype-polymorphic loads: T = storage type of INPUT tensors ----
template<typename T> struct WT;
template<> struct WT<bf16> {
  static __device__ __forceinline__ float ld(const void* p, size_t i) {
    return bf2f(((const unsigned short*)p)[i]);
  }
  static __device__ __forceinline__ void ld4(const void* p, size_t i, float* d) {
    const ushort4 v = *(const ushort4*)((const unsigned short*)p + i);
    d[0]=bf2f(v.x); d[1]=bf2f(v.y); d[2]=bf2f(v.z); d[3]=bf2f(v.w);
  }
};
template<> struct WT<float> {
  static __device__ __forceinline__ float ld(const void* p, size_t i) {
    return ((const float*)p)[i];
  }
  static __device__ __forceinline__ void ld4(const void* p, size_t i, float* d) {
    const float4 v = *(const float4*)((const float*)p + i);
    d[0]=v.x; d[1]=v.y; d[2]=v.z; d[3]=v.w;
  }
};

// ---- dtype detect: low u16 of each u32 word of x. bf16 buffer -> bf16 N(0,1)
// samples (sane magnitude, ~100%); fp32 buffer -> mantissa bits (sane ~4%). ----
__global__ void detect_k(const unsigned int* __restrict__ x, int* __restrict__ flag) {
  int tid = threadIdx.x;
  int cnt = 0;
  for (int i = tid; i < 256; i += 64) {
    float a = fabsf(bf2f((unsigned short)(x[i] & 0xffffu)));
    if (a > 1e-3f && a < 10.f) cnt++;
  }
  for (int off = 32; off >= 1; off >>= 1) cnt += __shfl_xor(cnt, off);
  if (tid == 0) *flag = (cnt >= 128) ? 1 : 0;
}

// ---- scalar-VALU GEMM (round-2 proven): C = epi(A @ W^T + bias) ----
// mode 0: plain, 1: +bias,silu, 2: +bias,softplus.  M%64==0, N%64==0, K%16==0.
template<typename TA, typename TWt>
__device__ __forceinline__ void gemm_body(
    const void* __restrict__ A, const void* __restrict__ W,
    const void* __restrict__ bias, float* __restrict__ C,
    int K, int lda, int ldb, int ldc, int mode)
{
  __shared__ float As[16][68];
  __shared__ float Bs[16][68];
  const int tid = threadIdx.x;
  const int m0 = blockIdx.x * 64;
  const int n0 = blockIdx.y * 64;
  const int tx = tid & 15, ty = tid >> 4;
  const int lrow = tid >> 2;        // 0..63
  const int lk4  = (tid & 3) * 4;   // 0,4,8,12
  float acc[4][4] = {};
  for (int k0 = 0; k0 < K; k0 += 16) {
    float av[4], bv[4];
    WT<TA >::ld4(A, (size_t)(m0 + lrow) * lda + k0 + lk4, av);
    WT<TWt>::ld4(W, (size_t)(n0 + lrow) * ldb + k0 + lk4, bv);
    __syncthreads();
    #pragma unroll
    for (int q = 0; q < 4; ++q) { As[lk4+q][lrow] = av[q]; Bs[lk4+q][lrow] = bv[q]; }
    __syncthreads();
    #pragma unroll
    for (int k = 0; k < 16; ++k) {
      float4 a4 = *(const float4*)&As[k][ty*4];
      float4 b4 = *(const float4*)&Bs[k][tx*4];
      float aa[4] = {a4.x, a4.y, a4.z, a4.w};
      float bb[4] = {b4.x, b4.y, b4.z, b4.w};
      #pragma unroll
      for (int i = 0; i < 4; ++i)
        #pragma unroll
        for (int j = 0; j < 4; ++j)
          acc[i][j] += aa[i] * bb[j];
    }
  }
  #pragma unroll
  for (int i = 0; i < 4; ++i) {
    int m = m0 + ty*4 + i;
    int n = n0 + tx*4;
    float o[4];
    #pragma unroll
    for (int j = 0; j < 4; ++j) {
      float v = acc[i][j];
      if (mode >= 1) v += WT<TWt>::ld(bias, n + j);
      if (mode == 1) v = v * sigmoidf_(v);
      else if (mode == 2) v = (v > 20.f) ? v : log1pf(__expf(v));
      o[j] = v;
    }
    *(float4*)&C[(size_t)m * ldc + n] = make_float4(o[0], o[1], o[2], o[3]);
  }
}

// A is a raw INPUT tensor (dtype = flag)
__global__ __launch_bounds__(256) void gemm_in_k(const void* A, const void* W,
    const void* bias, float* C, int K, int lda, int ldb, int ldc, int mode,
    const int* __restrict__ flag)
{
  if (*flag) gemm_body<bf16, bf16>(A, W, bias, C, K, lda, ldb, ldc, mode);
  else       gemm_body<float, float>(A, W, bias, C, K, lda, ldb, ldc, mode);
}
// A is an fp32 workspace tensor
__global__ __launch_bounds__(256) void gemm_ws_k(const void* A, const void* W,
    const void* bias, float* C, int K, int lda, int ldb, int ldc, int mode,
    const int* __restrict__ flag)
{
  if (*flag) gemm_body<float, bf16>(A, W, bias, C, K, lda, ldb, ldc, mode);
  else       gemm_body<float, float>(A, W, bias, C, K, lda, ldb, ldc, mode);
}

// ---- MFMA GEMM (bisect target): C = epi(A @ W^T + bias), fp32 A staged->bf16.
// 128x128 tile, BK=32, 4 waves x (64x64 via 4x4 16x16x32 mfma).
// Requires M % 128 == 0, N % 128 == 0, K % 32 == 0 (no edge handling).
// mode 0: plain fp32 store; 2: +bias, softplus, fp32 store.
template<typename TWt>
__device__ __forceinline__ void mfma_body(
    const float* __restrict__ A, const void* __restrict__ Wv,
    const void* __restrict__ biasv, float* __restrict__ C,
    int K, int lda, int ldb, int ldc, int mode)
{
  __shared__ unsigned short As[128*40];   // 32 data + 8 pad per row
  __shared__ unsigned short Bs[128*40];
  const int tid = threadIdx.x;
  const int m0 = blockIdx.x * 128;
  const int n0 = blockIdx.y * 128;
  const int lane = tid & 63;
  const int wv = tid >> 6;
  const int wm = (wv >> 1) * 64, wn = (wv & 1) * 64;
  const int lr = lane & 15, lg = lane >> 4;

  f32x4 acc[4][4];
  #pragma unroll
  for (int i = 0; i < 4; ++i)
    #pragma unroll
    for (int j = 0; j < 4; ++j) acc[i][j] = (f32x4){0.f, 0.f, 0.f, 0.f};

  for (int k0 = 0; k0 < K; k0 += 32) {
    // stage 128x32 tiles: 512 chunks of 8 elems, 2 chunks/thread
    short8 ra[2], rb[2];
    #pragma unroll
    for (int r = 0; r < 2; ++r) {
      int chunk = tid + r*256;
      int row = chunk >> 2, sub = (chunk & 3) * 8;
      {  // A: fp32 -> bf16
        const float* ap = A + (size_t)(m0 + row)*lda + k0 + sub;
        float4 f0 = *(const float4*)ap;
        float4 f1 = *(const float4*)(ap + 4);
        short8 v;
        v[0]=(short)f2bfbits(f0.x); v[1]=(short)f2bfbits(f0.y);
        v[2]=(short)f2bfbits(f0.z); v[3]=(short)f2bfbits(f0.w);
        v[4]=(short)f2bfbits(f1.x); v[5]=(short)f2bfbits(f1.y);
        v[6]=(short)f2bfbits(f1.z); v[7]=(short)f2bfbits(f1.w);
        ra[r] = v;
      }
      if (sizeof(TWt) == 2) {
        rb[r] = *(const short8*)((const unsigned short*)Wv + (size_t)(n0 + row)*ldb + k0 + sub);
      } else {
        const float* wp = (const float*)Wv + (size_t)(n0 + row)*ldb + k0 + sub;
        float4 f0 = *(const float4*)wp;
        float4 f1 = *(const float4*)(wp + 4);
        short8 v;
        v[0]=(short)f2bfbits(f0.x); v[1]=(short)f2bfbits(f0.y);
        v[2]=(short)f2bfbits(f0.z); v[3]=(short)f2bfbits(f0.w);
        v[4]=(short)f2bfbits(f1.x); v[5]=(short)f2bfbits(f1.y);
        v[6]=(short)f2bfbits(f1.z); v[7]=(short)f2bfbits(f1.w);
        rb[r] = v;
      }
    }
    __syncthreads();                       // prior iter's frag reads done
    #pragma unroll
    for (int r = 0; r < 2; ++r) {
      int chunk = tid + r*256;
      int row = chunk >> 2, sub = (chunk & 3) * 8;
      *(short8*)&As[row*40 + sub] = ra[r];
      *(short8*)&Bs[row*40 + sub] = rb[r];
    }
    __syncthreads();
    // fragments: A[m=lane&15][k=quad*8+j], B[n=lane&15][k=quad*8+j]
    short8 af[4], bfr[4];
    #pragma unroll
    for (int i = 0; i < 4; ++i)
      af[i] = *(const short8*)&As[(wm + i*16 + lr)*40 + lg*8];
    #pragma unroll
    for (int j = 0; j < 4; ++j)
      bfr[j] = *(const short8*)&Bs[(wn + j*16 + lr)*40 + lg*8];
    #pragma unroll
    for (int i = 0; i < 4; ++i)
      #pragma unroll
      for (int j = 0; j < 4; ++j)
        acc[i][j] = __builtin_amdgcn_mfma_f32_16x16x32_bf16(af[i], bfr[j], acc[i][j], 0, 0, 0);
  }

  // C/D layout: col=lane&15, row=(lane>>4)*4+reg  [m89/m91 verified]
  #pragma unroll
  for (int j = 0; j < 4; ++j) {
    int gn = n0 + wn + j*16 + lr;
    float bv = 0.f;
    if (mode == 2) bv = WT<TWt>::ld(biasv, gn);
    #pragma unroll
    for (int i = 0; i < 4; ++i) {
      #pragma unroll
      for (int r = 0; r < 4; ++r) {
        int gm = m0 + wm + i*16 + lg*4 + r;
        float v = acc[i][j][r];
        if (mode == 2) { v += bv; v = (v > 20.f) ? v : log1pf(__expf(v)); }
        C[(size_t)gm*ldc + gn] = v;
      }
    }
  }
}
__global__ __launch_bounds__(256) void gemm_mfma_k(const float* A, const void* W,
    const void* bias, float* C, int K, int lda, int ldb, int ldc, int mode,
    const int* __restrict__ flag)
{
  if (*flag) mfma_body<bf16>(A, W, bias, C, K, lda, ldb, ldc, mode);
  else       mfma_body<float>(A, W, bias, C, K, lda, ldb, ldc, mode);
}

// ---- z (gate) only needed at last token ----
template<typename TWt>
__device__ __forceinline__ void zlast_body(const float* __restrict__ embed,
    const void* __restrict__ W_in, float* __restrict__ z_last)
{
  int b = blockIdx.x;
  __shared__ float e[DM];
  for (int i = threadIdx.x; i < DM; i += 256) e[i] = embed[(size_t)(b*L_ + L_-1)*DM + i];
  __syncthreads();
  for (int j = threadIdx.x; j < DI; j += 256) {
    size_t roff = (size_t)(DI + j)*DM;
    float acc = 0.f;
    for (int k = 0; k < DM; ++k) acc += e[k]*WT<TWt>::ld(W_in, roff + k);
    z_last[b*DI + j] = acc;
  }
}
__global__ __launch_bounds__(256) void zlast_k(const float* embed, const void* W_in,
    float* z_last, const int* __restrict__ flag)
{
  if (*flag) zlast_body<bf16>(embed, W_in, z_last);
  else       zlast_body<float>(embed, W_in, z_last);
}

// ---- causal depthwise conv + silu ----
template<typename TWt>
__device__ __forceinline__ void conv_body(const float* __restrict__ xu,
    const void* __restrict__ conv_w, const void* __restrict__ conv_b,
    float* __restrict__ u)
{
  int bi = blockIdx.x;                    // 1024 blocks = b(16) x tc(16) x dchunk(4)
  int d  = (bi & 3)*256 + threadIdx.x;
  int tc = (bi >> 2) & 15;
  int b  = bi >> 6;
  float w[4];
  WT<TWt>::ld4(conv_w, (size_t)d*4, w);
  float bias = WT<TWt>::ld(conv_b, d);
  int t0 = tc*64;
  const float* base = xu + (size_t)b*L_*DI + d;
  float* ubase = u + (size_t)b*L_*DI + d;
  float xm3 = (t0-3 >= 0) ? base[(size_t)(t0-3)*DI] : 0.f;
  float xm2 = (t0-2 >= 0) ? base[(size_t)(t0-2)*DI] : 0.f;
  float xm1 = (t0-1 >= 0) ? base[(size_t)(t0-1)*DI] : 0.f;
  for (int t = t0; t < t0+64; ++t) {
    float cur = base[(size_t)t*DI];
    float v = w[0]*xm3 + w[1]*xm2 + w[2]*xm1 + w[3]*cur + bias;
    ubase[(size_t)t*DI] = v * sigmoidf_(v);
    xm3 = xm2; xm2 = xm1; xm1 = cur;
  }
}
__global__ __launch_bounds__(256) void conv_k(const float* xu, const void* conv_w,
    const void* conv_b, float* u, const int* __restrict__ flag)
{
  if (*flag) conv_body<bf16>(xu, conv_w, conv_b, u);
  else       conv_body<float>(xu, conv_w, conv_b, u);
}

// ---- selective scan: thread = (dl 0..15, n 0..15); only last-token y needed ----
template<typename TWt>
__device__ __forceinline__ void scan_body(const float* __restrict__ delta,
    const float* __restrict__ u, const float* __restrict__ xdbl,
    const void* __restrict__ A_log, float* __restrict__ y_scan)
{
  int b = blockIdx.x;
  int d0 = blockIdx.y * 16;
  int tid = threadIdx.x;
  int n = tid & 15, dl = tid >> 4;
  int d = d0 + dl;
  float a = -__expf(WT<TWt>::ld(A_log, (size_t)d*NST + n));
  __shared__ float sD[128*16], sU[128*16], sB[128*16];
  float h = 0.f;
  for (int t0 = 0; t0 < L_; t0 += 128) {
    __syncthreads();
    for (int i = tid; i < 128*16; i += 256) {
      int tt = i >> 4, q = i & 15;
      size_t row = (size_t)(b*L_ + t0 + tt);
      sD[i] = delta[row*DI + d0 + q];
      sU[i] = u[row*DI + d0 + q];
      sB[i] = xdbl[row*64 + DTR + q];
    }
    __syncthreads();
    #pragma unroll 8
    for (int t = 0; t < 128; ++t) {
      float dt = sD[t*16 + dl];
      float ut = sU[t*16 + dl];
      float bn = sB[t*16 + n];
      h = __expf(dt * a) * h + dt * ut * bn;
    }
  }
  float c = xdbl[(size_t)(b*L_ + L_-1)*64 + DTR + NST + n];
  float p = h * c;
  p += __shfl_xor(p, 1);
  p += __shfl_xor(p, 2);
  p += __shfl_xor(p, 4);
  p += __shfl_xor(p, 8);
  if (n == 0) y_scan[b*DI + d] = p;
}
__global__ __launch_bounds__(256) void scan_k(const float* delta, const float* u,
    const float* xdbl, const void* A_log, float* y_scan, const int* __restrict__ flag)
{
  if (*flag) scan_body<bf16>(delta, u, xdbl, A_log, y_scan);
  else       scan_body<float>(delta, u, xdbl, A_log, y_scan);
}

// ---- last-token epilogue: y*silu(z) -> W_out -> layernorm -> silu -> 17 heads ----
template<typename TWt>
__device__ __forceinline__ void head_body(const float* __restrict__ y_scan,
    const float* __restrict__ u, const float* __restrict__ z_last,
    const void* __restrict__ Dskip, const void* __restrict__ W_out,
    const void* __restrict__ W_critic, const void* __restrict__ b_critic,
    const void* __restrict__ W_amean, const void* __restrict__ b_amean,
    const void* __restrict__ W_astd, const void* __restrict__ b_astd,
    void* __restrict__ out)
{
  int b = blockIdx.x;
  int tid = threadIdx.x;
  __shared__ float yz[DI];
  __shared__ float nb[DM];
  __shared__ float w1[8], w2[8];
  for (int i = tid; i < DI; i += 512) {
    float ys = y_scan[b*DI + i] + u[(size_t)(b*L_ + L_-1)*DI + i] * WT<TWt>::ld(Dskip, i);
    float z = z_last[b*DI + i];
    yz[i] = ys * (z * sigmoidf_(z));
  }
  __syncthreads();
  float m = 0.f;
  {
    size_t roff = (size_t)tid * DI;
    for (int k = 0; k < DI; ++k) m += yz[k] * WT<TWt>::ld(W_out, roff + k);
  }
  float s1 = m, s2 = m*m;
  for (int off = 32; off >= 1; off >>= 1) { s1 += __shfl_xor(s1, off); s2 += __shfl_xor(s2, off); }
  int wid = tid >> 6, lane = tid & 63;
  if (lane == 0) { w1[wid] = s1; w2[wid] = s2; }
  __syncthreads();
  float t1 = 0.f, t2 = 0.f;
  for (int i = 0; i < 8; ++i) { t1 += w1[i]; t2 += w2[i]; }
  float mu  = t1 * (1.f/DM);
  float var = t2 * (1.f/DM) - mu*mu;
  float v = (m - mu) * rsqrtf(var + 1e-5f);
  nb[tid] = v * sigmoidf_(v);
  __syncthreads();
  for (int o = wid; o < 17; o += 8) {
    const void* w; size_t woff; float bias;
    if (o < 8)       { w = W_amean; woff = (size_t)o*DM;     bias = WT<TWt>::ld(b_amean, o); }
    else if (o < 16) { w = W_astd;  woff = (size_t)(o-8)*DM; bias = WT<TWt>::ld(b_astd, o-8); }
    else             { w = W_critic; woff = 0;               bias = WT<TWt>::ld(b_critic, 0); }
    float p = 0.f;
    for (int j = lane; j < DM; j += 64) p += nb[j] * WT<TWt>::ld(w, woff + j);
    for (int off = 32; off >= 1; off >>= 1) p += __shfl_xor(p, off);
    if (lane == 0) {
      float r = p + bias;
      int idx; float val;
      if (o < 8)       { idx = b*8 + o;           val = r; }
      else if (o < 16) { float ls = fminf(1.f, fmaxf(-1.f, r));
                         idx = 128 + b*8 + (o-8); val = expf(ls); }
      else             { idx = 256 + b;           val = r; }
      if (sizeof(TWt) == 2) ((bf16*)out)[idx] = __float2bfloat16(val);
      else                  ((float*)out)[idx] = val;
    }
  }
}
__global__ __launch_bounds__(512) void head_k(const float* y_scan, const float* u,
    const float* z_last, const void* Dskip, const void* W_out,
    const void* W_critic, const void* b_critic, const void* W_amean,
    const void* b_amean, const void* W_astd, const void* b_astd,
    void* out, const int* __restrict__ flag)
{
  if (*flag) head_body<bf16>(y_scan, u, z_last, Dskip, W_out, W_critic, b_critic,
                             W_amean, b_amean, W_astd, b_astd, out);
  else       head_body<float>(y_scan, u, z_last, Dskip, W_out, W_critic, b_critic,
                              W_amean, b_amean, W_astd, b_astd, out);
}

extern "C" void kernel_launch(void* const* d_in, const int* in_sizes, int n_in,
                              void* d_out, int out_size, void* d_ws, size_t ws_size,
                              hipStream_t stream)
{
  const void* x        = d_in[0];
  const void* W_emb    = d_in[1];
  const void* b_emb    = d_in[2];
  const void* W_in     = d_in[3];
  const void* conv_w   = d_in[4];
  const void* conv_b   = d_in[5];
  const void* W_xproj  = d_in[6];
  const void* W_dt     = d_in[7];
  const void* b_dt     = d_in[8];
  const void* A_log    = d_in[9];
  const void* Dskip    = d_in[10];
  const void* W_out    = d_in[11];
  const void* W_critic = d_in[12];
  const void* b_critic = d_in[13];
  const void* W_amean  = d_in[14];
  const void* b_amean  = d_in[15];
  const void* W_astd   = d_in[16];
  const void* b_astd   = d_in[17];

  // workspace layout (fp32 intermediates): 32+64+64+4 MB + small = ~164.2 MB
  char* ws = (char*)d_ws;
  float* embed = (float*)ws; ws += (size_t)ML*DM*sizeof(float);
  float* xu    = (float*)ws; ws += (size_t)ML*DI*sizeof(float);
  float* uu    = (float*)ws; ws += (size_t)ML*DI*sizeof(float);
  float* xdbl  = (float*)ws; ws += (size_t)ML*64*sizeof(float);
  float* zlast = (float*)ws; ws += (size_t)B_*DI*sizeof(float);
  float* yscan = (float*)ws; ws += (size_t)B_*DI*sizeof(float);
  int*   flag  = (int*)ws;   ws += 64;
  float* delta = xu;  // xu is dead after conv; reuse for delta

  // 0. detect input dtype (bf16 vs fp32) from x's bit patterns
  detect_k<<<1, 64, 0, stream>>>((const unsigned int*)x, flag);
  // 1. embed = silu(x @ W_emb^T + b_emb)   [scalar, proven]
  gemm_in_k<<<dim3(ML/64, DM/64), 256, 0, stream>>>(x, W_emb, b_emb, embed, 32, 32, 32, DM, 1, flag);
  // 2. xu = embed @ W_in[:DI]^T   [** MFMA bisect target #1 **]
  gemm_mfma_k<<<dim3(ML/128, DI/128), 256, 0, stream>>>(embed, W_in, nullptr, xu,
                                                        DM, DM, DM, DI, 0, flag);
  // 2b. z at last token only   [scalar, proven]
  zlast_k<<<16, 256, 0, stream>>>(embed, W_in, zlast, flag);
  // 3. u = silu(causal depthwise conv(xu))   [proven]
  conv_k<<<1024, 256, 0, stream>>>(xu, conv_w, conv_b, uu, flag);
  // 4. x_dbl = u @ W_xproj^T  (dt | B | C)   [scalar, proven]
  gemm_ws_k<<<dim3(ML/64, 1), 256, 0, stream>>>(uu, W_xproj, nullptr, xdbl, DI, DI, DI, 64, 0, flag);
  // 5. delta = softplus(dt @ W_dt^T + b_dt)  [** MFMA bisect target #2 **]
  gemm_mfma_k<<<dim3(ML/128, DI/128), 256, 0, stream>>>(xdbl, W_dt, b_dt, delta,
                                                        32, 64, 32, DI, 2, flag);
  // 6. selective scan -> y at last token   [proven]
  scan_k<<<dim3(B_, DI/16), 256, 0, stream>>>(delta, uu, xdbl, A_log, yscan, flag);
  // 7. gate, out-proj, layernorm, silu, heads   [proven]
  head_k<<<16, 512, 0, stream>>>(yscan, uu, zlast, Dskip, W_out, W_critic, b_critic,
                                 W_amean, b_amean, W_astd, b_astd, (void*)d_out, flag);
}